// Round 9
// baseline (7673.744 us; speedup 1.0000x reference)
//
#include <hip/hip_runtime.h>
#include <cstdint>
#include <cstddef>

#define TT   512
#define NWG  256
#define SLOT 65536            // floats per timestep slot in d_out
#define SLOTB 262144          // bytes per slot
#define FINALOFF ((size_t)TT * (size_t)SLOT)

// ws layout (bytes)
#define OFF_M    0                          // M f16: 2 MiB
#define XB_H0    2097152                    // each act buffer: 4 quad * 16384 f16 = 128 KiB
#define XB_TH0   (XB_H0 + 131072)
#define XB_TH1   (XB_TH0 + 131072)
#define XB_H1A   (XB_TH1 + 131072)
#define XB_H1B   (XB_H1A + 131072)
#define OFF_B0   (XB_H1B + 131072)          // 1024 f32
#define OFF_C1   (OFF_B0 + 4096)            // 1024 f32
#define OFF_CNT  (OFF_C1 + 4096)            // 4 quads * 64 u32 (cA at q*64, cB at q*64+32)

typedef _Float16 f16;
typedef unsigned long long ull;
typedef _Float16 v8h __attribute__((ext_vector_type(8)));
typedef float v4f __attribute__((ext_vector_type(4)));

union U2 { ull u[2]; v8h v; };
union P4 { f16 h[4]; ull u; };

__device__ __forceinline__ void st2(void* p, f16 v) {
  __hip_atomic_store((unsigned short*)p, __builtin_bit_cast(unsigned short, v),
                     __ATOMIC_RELAXED, __HIP_MEMORY_SCOPE_AGENT);
}
__device__ __forceinline__ f16 ld2(const void* p) {
  unsigned short u = __hip_atomic_load((const unsigned short*)p,
                                       __ATOMIC_RELAXED, __HIP_MEMORY_SCOPE_AGENT);
  return __builtin_bit_cast(f16, u);
}
__device__ __forceinline__ ull ld8(const void* p) {
  return __hip_atomic_load((const ull*)p, __ATOMIC_RELAXED, __HIP_MEMORY_SCOPE_AGENT);
}
__device__ __forceinline__ void cadd(unsigned int* c) {
  __hip_atomic_fetch_add(c, 1u, __ATOMIC_RELAXED, __HIP_MEMORY_SCOPE_AGENT);
}
__device__ __forceinline__ void cpoll(const unsigned int* c, unsigned int tgt) {
  while (__hip_atomic_load(c, __ATOMIC_RELAXED, __HIP_MEMORY_SCOPE_AGENT) < tgt) {}
}

// frags: 8 x 16B at stride 512 f16 (per-WG 256B blocks, 2 blocks/frag-stride)
__device__ __forceinline__ void ld_frags8(const f16* base, v8h out[8]) {
  ull u0[8], u1[8];
#pragma unroll
  for (int s = 0; s < 8; ++s) { const f16* p = base + s * 512; u0[s] = ld8(p); u1[s] = ld8(p + 4); }
#pragma unroll
  for (int s = 0; s < 8; ++s) { U2 c; c.u[0] = u0[s]; c.u[1] = u1[s]; out[s] = c.v; }
}

__device__ __forceinline__ float rcpf(float x) {
#if __has_builtin(__builtin_amdgcn_rcpf)
  return __builtin_amdgcn_rcpf(x);
#else
  return 1.0f / x;
#endif
}
__device__ __forceinline__ float tanhfast(float x) {
  x = fminf(fmaxf(x, -20.0f), 20.0f);
  const float u = __expf(-2.0f * x);
  return 1.0f - 2.0f * u * rcpf(1.0f + u);
}

__global__ void k_init(unsigned int* cnt) {
  cnt[threadIdx.x] = 0u;  // 256 u32 cover all quadrant counters
}

// b0[i] = bi0+bh0 ; c1[i] = Wi1.bo0 + bi1 + bh1
__global__ void k_bias(const float* __restrict__ Wi, const float* __restrict__ bi,
                       const float* __restrict__ bh, const float* __restrict__ bo,
                       float* __restrict__ b0, float* __restrict__ c1) {
  const int i = blockIdx.x * 256 + threadIdx.x;
  const float* row = Wi + 1048576 + (size_t)i * 1024;
  float s = 0.f;
  for (int k = 0; k < 1024; k += 4) {
    const float4 w = *(const float4*)&row[k];
    const float4 v = *(const float4*)&bo[k];
    s += w.x * v.x + w.y * v.y + w.z * v.z + w.w * v.w;
  }
  c1[i] = s + bi[1024 + i] + bh[1024 + i];
  b0[i] = bi[i] + bh[i];
}

// M[i][d] = sum_k Wi1[i][k] * Wo0[k][d]   (fp32 compute, f16 store) — proven
__global__ __launch_bounds__(256) void k_gemm_M(const float* __restrict__ Wi,
                                                const float* __restrict__ Wo,
                                                f16* __restrict__ Mh) {
  const float* A = Wi + 1048576;
  const float* B = Wo;
  __shared__ float As[16][68];
  __shared__ float Bs[16][68];
  const int bi = blockIdx.x >> 4, bj = blockIdx.x & 15;
  const int i0 = bi * 64, d0 = bj * 64;
  const int ti = threadIdx.x >> 4, tj = threadIdx.x & 15;
  float acc[4][4] = {};
  for (int kc = 0; kc < 1024; kc += 16) {
    const int r = threadIdx.x >> 2, cg = (threadIdx.x & 3) << 2;
    const float4 av = *(const float4*)&A[(size_t)(i0 + r) * 1024 + kc + cg];
    As[cg + 0][r] = av.x; As[cg + 1][r] = av.y; As[cg + 2][r] = av.z; As[cg + 3][r] = av.w;
    const int c2 = threadIdx.x >> 4, dg = (threadIdx.x & 15) << 2;
    const float4 bv = *(const float4*)&B[(size_t)(kc + c2) * 1024 + d0 + dg];
    *(float4*)&Bs[c2][dg] = bv;
    __syncthreads();
#pragma unroll
    for (int kk = 0; kk < 16; ++kk) {
      float a[4], b[4];
#pragma unroll
      for (int q = 0; q < 4; ++q) { a[q] = As[kk][ti * 4 + q]; b[q] = Bs[kk][tj * 4 + q]; }
#pragma unroll
      for (int p = 0; p < 4; ++p)
#pragma unroll
        for (int q = 0; q < 4; ++q) acc[p][q] += a[p] * b[q];
    }
    __syncthreads();
  }
#pragma unroll
  for (int p = 0; p < 4; ++p)
#pragma unroll
    for (int q = 0; q < 4; ++q)
      Mh[(size_t)(i0 + ti * 4 + p) * 1024 + (size_t)(d0 + tj * 4 + q)] = (f16)acc[p][q];
}

// z1(t) = x(t).Wi0^T + b0, f16, block layout inside d_out slot t:
// byte(t,q,jt8,b',j') = t*SLOTB + q*65536 + jt8*256 + (b'*8 + j')*2  (q=b>>4, b'=b&15, jt8=j>>3, j'=j&7)
__global__ __launch_bounds__(256, 1) void k_z1(const float* __restrict__ x,
                                               const float* __restrict__ Wi,
                                               const float* __restrict__ b0p,
                                               float* __restrict__ dout) {
  const int t = blockIdx.x;
  const int tid = threadIdx.x, l = tid & 63, w = tid >> 6;
  const int lj = l & 15, lk = l >> 4;
  __shared__ __align__(16) f16 XL[64 * 1032];
  const float* xt = x + (size_t)t * SLOT;
  for (int u = tid; u < 16384; u += 256) {
    const int b = u >> 8, c4 = (u & 255) << 2;
    const float4 v = *(const float4*)&xt[(size_t)b * 1024 + c4];
    P4 p; p.h[0] = (f16)v.x; p.h[1] = (f16)v.y; p.h[2] = (f16)v.z; p.h[3] = (f16)v.w;
    *(ull*)&XL[b * 1032 + c4] = p.u;
  }
  __syncthreads();
  for (int jtile = 0; jtile < 16; ++jtile) {
    const int jb = w * 256 + jtile * 16;
    v4f acc[4] = {{0.f,0.f,0.f,0.f},{0.f,0.f,0.f,0.f},{0.f,0.f,0.f,0.f},{0.f,0.f,0.f,0.f}};
    for (int ks = 0; ks < 32; ++ks) {
      const int k0 = ks * 32 + lk * 8;
      const float* p = &Wi[(size_t)(jb + lj) * 1024 + k0];
      const float4 a = *(const float4*)p, b = *(const float4*)(p + 4);
      const v8h wf = {(f16)a.x,(f16)a.y,(f16)a.z,(f16)a.w,
                      (f16)b.x,(f16)b.y,(f16)b.z,(f16)b.w};
#pragma unroll
      for (int bt = 0; bt < 4; ++bt) {
        const v8h xf = *(const v8h*)&XL[(bt * 16 + lj) * 1032 + k0];
        acc[bt] = __builtin_amdgcn_mfma_f32_16x16x32_f16(xf, wf, acc[bt], 0, 0, 0);
      }
    }
    const float bias = b0p[jb + lj];
    const int jt8 = w * 32 + jtile * 2 + (lj >> 3);
    const int jr = lj & 7;
#pragma unroll
    for (int bt = 0; bt < 4; ++bt)
#pragma unroll
      for (int q = 0; q < 4; ++q) {
        const int bp = lk * 4 + q;   // b within quadrant
        f16* dst = (f16*)((char*)dout + (size_t)t * SLOTB + (size_t)bt * 65536
                          + (size_t)jt8 * 256) + bp * 8 + jr;
        *dst = (f16)(acc[bt][q] + bias);
      }
  }
}

// ---- persistent RNN: 2 independent 128-WG machines, each interleaving 2 batch quadrants ----
// WG: pm = wg&1 (quadrants pm*2, pm*2+1), jt = wg>>1 (j-slice of 8)
// step: A(q0),A(q1) -> arrive(cA0,cA1) -> winA(z prefetch + out-MFMAs) ->
//       poll cA0 -> B(q0) -> poll cA1 -> B(q1) -> arrive(cB0,cB1) -> winB(out stores) -> poll cB0,cB1
__global__ __launch_bounds__(256, 1) void k_rnn(
    const float* __restrict__ Wh, const float* __restrict__ Wo,
    const float* __restrict__ bo,
    char* __restrict__ ws, float* __restrict__ dout)
{
  const f16* Mh = (const f16*)(ws + OFF_M);
  f16* h0B  = (f16*)(ws + XB_H0);
  f16* th0B = (f16*)(ws + XB_TH0);
  f16* th1B = (f16*)(ws + XB_TH1);
  f16* h1B[2] = { (f16*)(ws + XB_H1A), (f16*)(ws + XB_H1B) };
  const float* c1p = (const float*)(ws + OFF_C1);
  unsigned int* cnt = (unsigned int*)(ws + OFF_CNT);

  const int wg = blockIdx.x;
  const int pm = wg & 1;
  const int q0 = pm * 2, q1 = q0 + 1;
  const int jt = wg >> 1;        // 0..127
  const int j0 = jt * 8;
  const int tid = threadIdx.x;
  const int l = tid & 63, w = tid >> 6;
  const int lj = l & 15, lk = l >> 4;

  unsigned int* cA0 = cnt + q0 * 64; unsigned int* cB0 = cA0 + 32;
  unsigned int* cA1 = cnt + q1 * 64; unsigned int* cB1 = cA1 + 32;

  __shared__ __align__(16) f16 WL[4 * 8192];   // 64 KiB: mats 0=Wh0,1=M,2=Wh1,3=Wo1; [k/8][j:8][8]
  __shared__ float red[5120];                  // 20 KiB (1024 used; pads LDS -> 1 WG/CU)

  // ---- stage weights (8 j rows per mat) ----
  {
    const float* srcs[3] = { Wh, Wh + 1048576, Wo + 1048576 };
    const int mi[3] = { 0, 2, 3 };
#pragma unroll
    for (int m = 0; m < 3; ++m) {
      const float* src = srcs[m];
      const int mo = mi[m] * 8192;
      for (int u = tid; u < 2048; u += 256) {
        const int j = u >> 8, c4 = (u & 255) << 2;
        const float4 v = *(const float4*)&src[(size_t)(j0 + j) * 1024 + c4];
        P4 p; p.h[0] = (f16)v.x; p.h[1] = (f16)v.y; p.h[2] = (f16)v.z; p.h[3] = (f16)v.w;
        *(ull*)&WL[mo + ((c4 >> 3) << 6) + (j << 3) + (c4 & 7)] = p.u;
      }
    }
    for (int u = tid; u < 1024; u += 256) {
      const int j = u >> 7, c8 = (u & 127) << 3;
      *(v8h*)&WL[8192 + ((c8 >> 3) << 6) + (j << 3)] = *(const v8h*)&Mh[(size_t)(j0 + j) * 1024 + c8];
    }
  }
  const bool act = (tid < 128);
  const int rb = tid >> 3, rj = tid & 7;
  float c1v = 0.f, bo1v = 0.f;
  if (act) { c1v = c1p[j0 + rj]; bo1v = bo[1024 + j0 + rj]; }
  __syncthreads();

  const int xb = (w * 32 + lk) * 128 + lj * 8;   // act frag base (+ s*512)
  const int xs = jt * 128 + tid;                 // act store slot (tid<128)
  const int redw = w * 256 + lk * 64 + lj;

  auto wfrag = [&](int m, int s) -> v8h {
    v8h r = {};
    if (lj < 8) r = *(const v8h*)&WL[m * 8192 + (w * 32 + s * 4 + lk) * 64 + lj * 8];
    return r;
  };
  auto reduce4 = [&](v4f a) -> float {
    __syncthreads();
#pragma unroll
    for (int q = 0; q < 4; ++q) red[redw + q * 16] = a[q];
    __syncthreads();
    float r = 0.f;
    if (act) { const int sl = rb * 16 + rj; r = red[sl] + red[256 + sl] + red[512 + sl] + red[768 + sl]; }
    return r;
  };
  auto zaddr = [&](int t, int q) -> const f16* {
    return (const f16*)((const char*)dout + (size_t)t * SLOTB + (size_t)q * 65536 + (size_t)jt * 256);
  };

  float zv0 = 0.f, zv1 = 0.f;
  if (act) { zv0 = (float)ld2(zaddr(0, q0) + tid); zv1 = (float)ld2(zaddr(0, q1) + tid); }

  v4f a2q0 = {0.f,0.f,0.f,0.f}, a2q1 = {0.f,0.f,0.f,0.f};

  for (int t = 0; t < TT; ++t) {
    const bool R = (t > 0);
    // ---------- phase A: h0 = z1 + Wh0*th1(t-1), both quadrants ----------
    {
      v4f acc = {0.f,0.f,0.f,0.f};
      if (R) {
        v8h thf[8]; ld_frags8(th1B + q0 * 16384 + xb, thf);
#pragma unroll
        for (int s = 0; s < 8; ++s)
          acc = __builtin_amdgcn_mfma_f32_16x16x32_f16(thf[s], wfrag(0, s), acc, 0, 0, 0);
      }
      const float h0 = reduce4(acc) + zv0;
      if (act) { st2(&h0B[q0 * 16384 + xs], (f16)h0); st2(&th0B[q0 * 16384 + xs], (f16)tanhfast(h0)); }
    }
    {
      v4f acc = {0.f,0.f,0.f,0.f};
      if (R) {
        v8h thf[8]; ld_frags8(th1B + q1 * 16384 + xb, thf);
#pragma unroll
        for (int s = 0; s < 8; ++s)
          acc = __builtin_amdgcn_mfma_f32_16x16x32_f16(thf[s], wfrag(0, s), acc, 0, 0, 0);
      }
      const float h0 = reduce4(acc) + zv1;
      if (act) { st2(&h0B[q1 * 16384 + xs], (f16)h0); st2(&th0B[q1 * 16384 + xs], (f16)tanhfast(h0)); }
    }
    asm volatile("s_waitcnt vmcnt(0)" ::: "memory");
    __syncthreads();
    if (tid == 0) { cadd(cA0); cadd(cA1); }
    asm volatile("" ::: "memory");

    // ---------- window A: z1(t+1) prefetch + out-GEMM MFMAs(t-1) ----------
    float zn0 = 0.f, zn1 = 0.f;
    if (t + 1 < TT && act) {
      zn0 = (float)ld2(zaddr(t + 1, q0) + tid);
      zn1 = (float)ld2(zaddr(t + 1, q1) + tid);
      asm volatile("" : "+v"(zn0), "+v"(zn1));
    }
    if (R) {
      v8h hrf[8];
      ld_frags8(h1B[(t - 1) & 1] + q0 * 16384 + xb, hrf);
      v4f aa = {0.f,0.f,0.f,0.f};
#pragma unroll
      for (int s = 0; s < 8; ++s)
        aa = __builtin_amdgcn_mfma_f32_16x16x32_f16(hrf[s], wfrag(3, s), aa, 0, 0, 0);
      a2q0 = aa;
      ld_frags8(h1B[(t - 1) & 1] + q1 * 16384 + xb, hrf);
      aa = (v4f){0.f,0.f,0.f,0.f};
#pragma unroll
      for (int s = 0; s < 8; ++s)
        aa = __builtin_amdgcn_mfma_f32_16x16x32_f16(hrf[s], wfrag(3, s), aa, 0, 0, 0);
      a2q1 = aa;
      asm volatile("" : "+v"(a2q0), "+v"(a2q1));
    }

    // ---------- phase B q0: h1 = M*h0 + Wh1*th0 + c1 ----------
    cpoll(cA0, 128u * (unsigned)(t + 1));
    {
      v8h g0f[8], t0f[8];
      ld_frags8(h0B + q0 * 16384 + xb, g0f);
      ld_frags8(th0B + q0 * 16384 + xb, t0f);
      v4f aM = {0.f,0.f,0.f,0.f}, aW = {0.f,0.f,0.f,0.f};
#pragma unroll
      for (int s = 0; s < 8; ++s) {
        aM = __builtin_amdgcn_mfma_f32_16x16x32_f16(g0f[s], wfrag(1, s), aM, 0, 0, 0);
        aW = __builtin_amdgcn_mfma_f32_16x16x32_f16(t0f[s], wfrag(2, s), aW, 0, 0, 0);
      }
      const float h1 = reduce4(aM + aW) + c1v;
      if (act) {
        const float th1v = tanhfast(h1);
        st2(&h1B[t & 1][q0 * 16384 + xs], (f16)h1);
        st2(&th1B[q0 * 16384 + xs], (f16)th1v);
        if (t == TT - 1) dout[FINALOFF + (size_t)(q0 * 16 + rb) * 1024 + j0 + rj] = th1v;
      }
    }
    // ---------- phase B q1 ----------
    cpoll(cA1, 128u * (unsigned)(t + 1));
    {
      v8h g0f[8], t0f[8];
      ld_frags8(h0B + q1 * 16384 + xb, g0f);
      ld_frags8(th0B + q1 * 16384 + xb, t0f);
      v4f aM = {0.f,0.f,0.f,0.f}, aW = {0.f,0.f,0.f,0.f};
#pragma unroll
      for (int s = 0; s < 8; ++s) {
        aM = __builtin_amdgcn_mfma_f32_16x16x32_f16(g0f[s], wfrag(1, s), aM, 0, 0, 0);
        aW = __builtin_amdgcn_mfma_f32_16x16x32_f16(t0f[s], wfrag(2, s), aW, 0, 0, 0);
      }
      const float h1 = reduce4(aM + aW) + c1v;
      if (act) {
        const float th1v = tanhfast(h1);
        st2(&h1B[t & 1][q1 * 16384 + xs], (f16)h1);
        st2(&th1B[q1 * 16384 + xs], (f16)th1v);
        if (t == TT - 1) dout[FINALOFF + (size_t)(q1 * 16 + rb) * 1024 + j0 + rj] = th1v;
      }
    }
    asm volatile("s_waitcnt vmcnt(0)" ::: "memory");
    __syncthreads();
    if (tid == 0) { cadd(cB0); cadd(cB1); }
    asm volatile("" ::: "memory");

    // ---------- window B: outs(t-1) reduce + store ----------
    if (R) {
      const float o0 = reduce4(a2q0) + bo1v;
      if (act) dout[(size_t)(t - 1) * SLOT + (size_t)(q0 * 16 + rb) * 1024 + j0 + rj] = o0;
      const float o1 = reduce4(a2q1) + bo1v;
      if (act) dout[(size_t)(t - 1) * SLOT + (size_t)(q1 * 16 + rb) * 1024 + j0 + rj] = o1;
    }
    cpoll(cB0, 128u * (unsigned)(t + 1));
    cpoll(cB1, 128u * (unsigned)(t + 1));
    zv0 = zn0; zv1 = zn1;
  }

  // ---------- epilogue: outs(TT-1) = Wo1*h1(TT-1) + bo1 ----------
  {
    v8h hrf[8];
    ld_frags8(h1B[(TT - 1) & 1] + q0 * 16384 + xb, hrf);
    v4f aa = {0.f,0.f,0.f,0.f};
#pragma unroll
    for (int s = 0; s < 8; ++s)
      aa = __builtin_amdgcn_mfma_f32_16x16x32_f16(hrf[s], wfrag(3, s), aa, 0, 0, 0);
    const float o0 = reduce4(aa) + bo1v;
    if (act) dout[(size_t)(TT - 1) * SLOT + (size_t)(q0 * 16 + rb) * 1024 + j0 + rj] = o0;
    ld_frags8(h1B[(TT - 1) & 1] + q1 * 16384 + xb, hrf);
    aa = (v4f){0.f,0.f,0.f,0.f};
#pragma unroll
    for (int s = 0; s < 8; ++s)
      aa = __builtin_amdgcn_mfma_f32_16x16x32_f16(hrf[s], wfrag(3, s), aa, 0, 0, 0);
    const float o1 = reduce4(aa) + bo1v;
    if (act) dout[(size_t)(TT - 1) * SLOT + (size_t)(q1 * 16 + rb) * 1024 + j0 + rj] = o1;
  }
}

extern "C" void kernel_launch(void* const* d_in, const int* in_sizes, int n_in,
                              void* d_out, int out_size, void* d_ws, size_t ws_size,
                              hipStream_t stream) {
  (void)in_sizes; (void)n_in; (void)out_size; (void)ws_size;
  const float* x  = (const float*)d_in[0];
  const float* Wi = (const float*)d_in[1];
  const float* bi = (const float*)d_in[2];
  const float* Wh = (const float*)d_in[3];
  const float* bh = (const float*)d_in[4];
  const float* Wo = (const float*)d_in[5];
  const float* bo = (const float*)d_in[6];
  char* ws = (char*)d_ws;
  float* out = (float*)d_out;

  k_init<<<1, 256, 0, stream>>>((unsigned int*)(ws + OFF_CNT));
  k_bias<<<4, 256, 0, stream>>>(Wi, bi, bh, bo, (float*)(ws + OFF_B0), (float*)(ws + OFF_C1));
  k_gemm_M<<<256, 256, 0, stream>>>(Wi, Wo, (f16*)(ws + OFF_M));
  k_z1<<<512, 256, 0, stream>>>(x, Wi, (const float*)(ws + OFF_B0), out);
  k_rnn<<<NWG, 256, 0, stream>>>(Wh, Wo, bo, ws, out);
}

// Round 10
// 6855.518 us; speedup vs baseline: 1.1194x; 1.1194x over previous
//
#include <hip/hip_runtime.h>
#include <cstdint>
#include <cstddef>

#define TT   512
#define NWG  256
#define SLOT 65536            // floats per timestep slot in d_out
#define SLOTB 262144          // bytes per slot
#define FINALOFF ((size_t)TT * (size_t)SLOT)

// ws layout (bytes)
#define OFF_M     0                         // M f16: 2 MiB
#define OFF_H0    2097152                   // 64*1024 f16 each (128 KiB)
#define OFF_TH0   (OFF_H0 + 131072)
#define OFF_TH1   (OFF_TH0 + 131072)
#define OFF_H1A   (OFF_TH1 + 131072)
#define OFF_H1B   (OFF_H1A + 131072)
#define OFF_B0    (OFF_H1B + 131072)        // 1024 f32
#define OFF_C1    (OFF_B0 + 4096)           // 1024 f32
#define OFF_FLAGS (OFF_C1 + 4096)           // 4 groups * 64 u32

typedef _Float16 f16;
typedef unsigned long long ull;
typedef _Float16 v8h __attribute__((ext_vector_type(8)));
typedef float v4f __attribute__((ext_vector_type(4)));

union U2 { ull u[2]; v8h v; };
union P4 { f16 h[4]; ull u; };

__device__ __forceinline__ void st2(void* p, f16 v) {
  __hip_atomic_store((unsigned short*)p, __builtin_bit_cast(unsigned short, v),
                     __ATOMIC_RELAXED, __HIP_MEMORY_SCOPE_AGENT);
}
__device__ __forceinline__ ull ld8(const void* p) {
  return __hip_atomic_load((const ull*)p, __ATOMIC_RELAXED, __HIP_MEMORY_SCOPE_AGENT);
}
__device__ __forceinline__ void ld_frags(const f16* base, v8h out[8]) {
  ull u0[8], u1[8];
#pragma unroll
  for (int s = 0; s < 8; ++s) { const f16* p = base + s * 32; u0[s] = ld8(p); u1[s] = ld8(p + 4); }
#pragma unroll
  for (int s = 0; s < 8; ++s) { U2 c; c.u[0] = u0[s]; c.u[1] = u1[s]; out[s] = c.v; }
}

__device__ __forceinline__ float rcpf(float x) {
#if __has_builtin(__builtin_amdgcn_rcpf)
  return __builtin_amdgcn_rcpf(x);
#else
  return 1.0f / x;
#endif
}
__device__ __forceinline__ float tanhfast(float x) {
  x = fminf(fmaxf(x, -20.0f), 20.0f);
  const float u = __expf(-2.0f * x);
  return 1.0f - 2.0f * u * rcpf(1.0f + u);
}

__global__ void k_init(unsigned int* flags) {
  flags[threadIdx.x] = 0u;  // 256 flags
}

// b0[i] = bi0+bh0 ; c1[i] = Wi1.bo0 + bi1 + bh1
__global__ void k_bias(const float* __restrict__ Wi, const float* __restrict__ bi,
                       const float* __restrict__ bh, const float* __restrict__ bo,
                       float* __restrict__ b0, float* __restrict__ c1) {
  const int i = blockIdx.x * 256 + threadIdx.x;
  const float* row = Wi + 1048576 + (size_t)i * 1024;
  float s = 0.f;
  for (int k = 0; k < 1024; k += 4) {
    const float4 w = *(const float4*)&row[k];
    const float4 v = *(const float4*)&bo[k];
    s += w.x * v.x + w.y * v.y + w.z * v.z + w.w * v.w;
  }
  c1[i] = s + bi[1024 + i] + bh[1024 + i];
  b0[i] = bi[i] + bh[i];
}

// M[i][d] = sum_k Wi1[i][k] * Wo0[k][d]   (fp32 compute, f16 store)
__global__ __launch_bounds__(256) void k_gemm_M(const float* __restrict__ Wi,
                                                const float* __restrict__ Wo,
                                                f16* __restrict__ Mh) {
  const float* A = Wi + 1048576;
  const float* B = Wo;
  __shared__ float As[16][68];
  __shared__ float Bs[16][68];
  const int bi = blockIdx.x >> 4, bj = blockIdx.x & 15;
  const int i0 = bi * 64, d0 = bj * 64;
  const int ti = threadIdx.x >> 4, tj = threadIdx.x & 15;
  float acc[4][4] = {};
  for (int kc = 0; kc < 1024; kc += 16) {
    const int r = threadIdx.x >> 2, cg = (threadIdx.x & 3) << 2;
    const float4 av = *(const float4*)&A[(size_t)(i0 + r) * 1024 + kc + cg];
    As[cg + 0][r] = av.x; As[cg + 1][r] = av.y; As[cg + 2][r] = av.z; As[cg + 3][r] = av.w;
    const int c2 = threadIdx.x >> 4, dg = (threadIdx.x & 15) << 2;
    const float4 bv = *(const float4*)&B[(size_t)(kc + c2) * 1024 + d0 + dg];
    *(float4*)&Bs[c2][dg] = bv;
    __syncthreads();
#pragma unroll
    for (int kk = 0; kk < 16; ++kk) {
      float a[4], b[4];
#pragma unroll
      for (int q = 0; q < 4; ++q) { a[q] = As[kk][ti * 4 + q]; b[q] = Bs[kk][tj * 4 + q]; }
#pragma unroll
      for (int p = 0; p < 4; ++p)
#pragma unroll
        for (int q = 0; q < 4; ++q) acc[p][q] += a[p] * b[q];
    }
    __syncthreads();
  }
#pragma unroll
  for (int p = 0; p < 4; ++p)
#pragma unroll
    for (int q = 0; q < 4; ++q)
      Mh[(size_t)(i0 + ti * 4 + p) * 1024 + (size_t)(d0 + tj * 4 + q)] = (f16)acc[p][q];
}

// z1(t) = x(t).Wi0^T + b0, f16, stored group-partitioned inside d_out slot t:
// byte(t,b,j) = t*SLOTB + (b>>4)*65536 + (b&15)*2048 + j*2
__global__ __launch_bounds__(256, 1) void k_z1(const float* __restrict__ x,
                                               const float* __restrict__ Wi,
                                               const float* __restrict__ b0p,
                                               float* __restrict__ dout) {
  const int t = blockIdx.x;
  const int tid = threadIdx.x, l = tid & 63, w = tid >> 6;
  const int lj = l & 15, lk = l >> 4;
  __shared__ __align__(16) f16 XL[64 * 1032];
  const float* xt = x + (size_t)t * SLOT;
  for (int u = tid; u < 16384; u += 256) {
    const int b = u >> 8, c4 = (u & 255) << 2;
    const float4 v = *(const float4*)&xt[(size_t)b * 1024 + c4];
    P4 p; p.h[0] = (f16)v.x; p.h[1] = (f16)v.y; p.h[2] = (f16)v.z; p.h[3] = (f16)v.w;
    *(ull*)&XL[b * 1032 + c4] = p.u;
  }
  __syncthreads();
  for (int jt = 0; jt < 16; ++jt) {
    const int jb = w * 256 + jt * 16;
    v4f acc[4] = {{0.f,0.f,0.f,0.f},{0.f,0.f,0.f,0.f},{0.f,0.f,0.f,0.f},{0.f,0.f,0.f,0.f}};
    for (int ks = 0; ks < 32; ++ks) {
      const int k0 = ks * 32 + lk * 8;
      const float* p = &Wi[(size_t)(jb + lj) * 1024 + k0];
      const float4 a = *(const float4*)p, b = *(const float4*)(p + 4);
      const v8h wf = {(f16)a.x,(f16)a.y,(f16)a.z,(f16)a.w,
                      (f16)b.x,(f16)b.y,(f16)b.z,(f16)b.w};
#pragma unroll
      for (int bt = 0; bt < 4; ++bt) {
        const v8h xf = *(const v8h*)&XL[(bt * 16 + lj) * 1032 + k0];
        acc[bt] = __builtin_amdgcn_mfma_f32_16x16x32_f16(xf, wf, acc[bt], 0, 0, 0);
      }
    }
    const float bias = b0p[jb + lj];
#pragma unroll
    for (int bt = 0; bt < 4; ++bt)
#pragma unroll
      for (int q = 0; q < 4; ++q) {
        const int b = bt * 16 + lk * 4 + q;
        f16* dst = (f16*)((char*)dout + (size_t)t * SLOTB + (size_t)(b >> 4) * 65536
                          + (size_t)(b & 15) * 2048) + (jb + lj);
        *dst = (f16)(acc[bt][q] + bias);
      }
  }
}

// ---- persistent RNN: 256 WGs (1/CU), weights LDS-resident, 4x64-WG groups ----
// R10 changes vs R8: counted-vmcnt drain overlap; out-GEMM between flagA and
// pollA (covers detect); dout stores after flagB drain (fly during pollB);
// th1 single-buffered (reads complete before overwrite); h1 double-buffered.
__global__ __launch_bounds__(256, 1) void k_rnn(
    const float* __restrict__ Wh, const float* __restrict__ Wo,
    const float* __restrict__ bo,
    char* __restrict__ ws, float* __restrict__ dout)
{
  const f16* Mh = (const f16*)(ws + OFF_M);
  f16* h0h  = (f16*)(ws + OFF_H0);
  f16* th0h = (f16*)(ws + OFF_TH0);
  f16* th1h = (f16*)(ws + OFF_TH1);
  f16* h1r[2] = { (f16*)(ws + OFF_H1A), (f16*)(ws + OFF_H1B) };
  const float* c1p = (const float*)(ws + OFF_C1);
  unsigned int* flags = (unsigned int*)(ws + OFF_FLAGS);

  const int wg = blockIdx.x;
  const int bq = wg & 3;
  const int jt = wg >> 2;
  const int j0 = jt * 16;
  const int tid = threadIdx.x;
  const int l = tid & 63, w = tid >> 6;
  const int lj = l & 15, lk = l >> 4;
  const int rb = tid >> 4, rj = tid & 15;
  unsigned int* gf = flags + bq * 64;

  __shared__ __align__(16) char WLb[4 * 32768];
  __shared__ float red[1024];

  // stage f32 mats: 0=Wh0, 2=Wh1, 3=Wo1; M (f16) -> mat 1
  {
    const float* srcs[3] = { Wh, Wh + 1048576, Wo + 1048576 };
    const int mi[3] = { 0, 2, 3 };
#pragma unroll
    for (int m = 0; m < 3; ++m) {
      const float* src = srcs[m];
      for (int u = tid; u < 4096; u += 256) {
        const int j = u >> 8, c4 = (u & 255) << 2;
        const float4 v = *(const float4*)&src[(size_t)(j0 + j) * 1024 + c4];
        P4 p; p.h[0] = (f16)v.x; p.h[1] = (f16)v.y; p.h[2] = (f16)v.z; p.h[3] = (f16)v.w;
        *(ull*)(WLb + mi[m] * 32768 + ((c4 >> 3) << 8) + (j << 4) + ((c4 & 4) << 1)) = p.u;
      }
    }
    for (int u = tid; u < 2048; u += 256) {
      const int j = u >> 7, c8 = (u & 127) << 3;
      const v8h mv = *(const v8h*)&Mh[(size_t)(j0 + j) * 1024 + c8];
      *(v8h*)(WLb + 32768 + ((c8 >> 3) << 8) + (j << 4)) = mv;
    }
  }
  const float c1v = c1p[j0 + rj];
  const float bo1v = bo[1024 + j0 + rj];
  __syncthreads();

  const size_t actbase = (size_t)(bq * 16 + lj) * 1024 + (size_t)(w * 256 + lk * 8);
  const int redw = w * 256 + lk * 64 + lj;
  const size_t rdst = (size_t)(bq * 16 + rb) * 1024 + (size_t)(j0 + rj);
  const int fbase = ((w * 32 + lk) << 8) + (lj << 4);

  auto wfrag = [&](int m, int s) -> v8h {
    return *(const v8h*)(WLb + m * 32768 + fbase + (s << 10));
  };
  auto zptr = [&](int t) -> const f16* {
    return (const f16*)((const char*)dout + (size_t)t * SLOTB + (size_t)bq * 65536
                        + (size_t)rb * 2048) + (j0 + rj);
  };
  auto reduce4 = [&](v4f a) -> float {
    __syncthreads();
#pragma unroll
    for (int q = 0; q < 4; ++q) red[redw + q * 16] = a[q];
    __syncthreads();
    return red[tid] + red[256 + tid] + red[512 + tid] + red[768 + tid];
  };
  auto pollge = [&](unsigned int ph) {
    if (tid < 64)
      while (__hip_atomic_load(&gf[tid], __ATOMIC_RELAXED, __HIP_MEMORY_SCOPE_AGENT) < ph)
        __builtin_amdgcn_s_sleep(1);
    __syncthreads();
    asm volatile("" ::: "memory");
  };
  auto setflag = [&](unsigned int ph) {
    if (tid == 0)
      __hip_atomic_store(&gf[jt], ph, __ATOMIC_RELAXED, __HIP_MEMORY_SCOPE_AGENT);
  };

  float zv = (float)(*zptr(0));
  v8h thf[8];

  for (int t = 0; t < TT; ++t) {
    const bool R = (t > 0);

    // ---- phase A: h0 = z1(t) + Wh0 * th1(t-1) ----
    v4f accA = {0.f, 0.f, 0.f, 0.f};
    if (R) {
#pragma unroll
      for (int s = 0; s < 8; ++s)
        accA = __builtin_amdgcn_mfma_f32_16x16x32_f16(thf[s], wfrag(0, s), accA, 0, 0, 0);
    }
    const float h0 = reduce4(accA) + zv;
    st2(&h0h[rdst], (f16)h0);
    st2(&th0h[rdst], (f16)tanhfast(h0));

    // ---- winA issue: h1(t-1) frags for out-GEMM + z1(t+1) prefetch ----
    v8h hrf[8];
    if (R) ld_frags(h1r[(t - 1) & 1] + actbase, hrf);   // 16 ld8 in flight
    float zn = 0.f;
    if (t + 1 < TT) zn = (float)(*zptr(t + 1));          // 1 plain load

    // counted drain: only the two st2s must be acked before flagA.
    // per-thread issue order: st2,st2,[16 ld8],[1 ld]; in-order retire.
    if (t == 0)            { asm volatile("s_waitcnt vmcnt(1)"  ::: "memory"); }
    else if (t == TT - 1)  { asm volatile("s_waitcnt vmcnt(16)" ::: "memory"); }
    else                   { asm volatile("s_waitcnt vmcnt(17)" ::: "memory"); }
    __syncthreads();
    setflag(2u * t + 1u);

    // ---- out-GEMM (covers other WGs' drain lag): outs(t-1) value ----
    float oval = 0.f;
    if (R) {
      asm volatile("s_waitcnt vmcnt(0)" ::: "memory");   // hrf + zn ready
      v4f aa = {0.f, 0.f, 0.f, 0.f};
#pragma unroll
      for (int s = 0; s < 8; ++s)
        aa = __builtin_amdgcn_mfma_f32_16x16x32_f16(hrf[s], wfrag(3, s), aa, 0, 0, 0);
      oval = reduce4(aa) + bo1v;
    }
    pollge(2u * t + 1u);

    // ---- phase B: h1 = M*h0 + Wh1*th0 + c1 ----
    v8h g0f[8], t0f[8];
    ld_frags(h0h + actbase, g0f);
    ld_frags(th0h + actbase, t0f);
    v4f aM = {0.f, 0.f, 0.f, 0.f}, aW = {0.f, 0.f, 0.f, 0.f};
#pragma unroll
    for (int s = 0; s < 8; ++s) {
      aM = __builtin_amdgcn_mfma_f32_16x16x32_f16(g0f[s], wfrag(1, s), aM, 0, 0, 0);
      aW = __builtin_amdgcn_mfma_f32_16x16x32_f16(t0f[s], wfrag(2, s), aW, 0, 0, 0);
    }
    const float h1 = reduce4(aM + aW) + c1v;
    const float th1v = tanhfast(h1);
    st2(&h1r[t & 1][rdst], (f16)h1);
    st2(&th1h[rdst], (f16)th1v);
    if (R) dout[(size_t)(t - 1) * SLOT + rdst] = oval;         // plain store
    if (t == TT - 1) dout[FINALOFF + rdst] = th1v;             // plain store

    // counted drain: only the two st2s; dout stores keep flying during pollB.
    if (t == 0)            { asm volatile("s_waitcnt vmcnt(0)" ::: "memory"); }
    else if (t == TT - 1)  { asm volatile("s_waitcnt vmcnt(2)" ::: "memory"); }
    else                   { asm volatile("s_waitcnt vmcnt(1)" ::: "memory"); }
    __syncthreads();
    setflag(2u * t + 2u);
    pollge(2u * t + 2u);

    if (t + 1 < TT) ld_frags(th1h + actbase, thf);   // completes before next flagA
    zv = zn;
  }

  // ---- epilogue: outs(TT-1) = Wo1 * h1(TT-1) + bo1 ----
  {
    v8h hrf[8];
    ld_frags(h1r[(TT - 1) & 1] + actbase, hrf);
    v4f aa = {0.f, 0.f, 0.f, 0.f};
#pragma unroll
    for (int s = 0; s < 8; ++s)
      aa = __builtin_amdgcn_mfma_f32_16x16x32_f16(hrf[s], wfrag(3, s), aa, 0, 0, 0);
    dout[(size_t)(TT - 1) * SLOT + rdst] = reduce4(aa) + bo1v;
  }
}

extern "C" void kernel_launch(void* const* d_in, const int* in_sizes, int n_in,
                              void* d_out, int out_size, void* d_ws, size_t ws_size,
                              hipStream_t stream) {
  (void)in_sizes; (void)n_in; (void)out_size; (void)ws_size;
  const float* x  = (const float*)d_in[0];
  const float* Wi = (const float*)d_in[1];
  const float* bi = (const float*)d_in[2];
  const float* Wh = (const float*)d_in[3];
  const float* bh = (const float*)d_in[4];
  const float* Wo = (const float*)d_in[5];
  const float* bo = (const float*)d_in[6];
  char* ws = (char*)d_ws;
  float* out = (float*)d_out;

  k_init<<<1, 256, 0, stream>>>((unsigned int*)(ws + OFF_FLAGS));
  k_bias<<<4, 256, 0, stream>>>(Wi, bi, bh, bo, (float*)(ws + OFF_B0), (float*)(ws + OFF_C1));
  k_gemm_M<<<256, 256, 0, stream>>>(Wi, Wo, (f16*)(ws + OFF_M));
  k_z1<<<512, 256, 0, stream>>>(x, Wi, (const float*)(ws + OFF_B0), out);
  k_rnn<<<NWG, 256, 0, stream>>>(Wh, Wo, bo, ws, out);
}

// Round 11
// 6402.211 us; speedup vs baseline: 1.1986x; 1.0708x over previous
//
#include <hip/hip_runtime.h>
#include <cstdint>
#include <cstddef>

#define TT   512
#define NWG  256
#define SLOT 65536            // floats per timestep slot in d_out
#define SLOTB 262144          // bytes per slot
#define FINALOFF ((size_t)TT * (size_t)SLOT)

// ws layout (bytes)
#define OFF_M    0                          // M f16: 2 MiB
#define OFF_X    2097152                    // exchange: 8 bufs x 128 KiB (order below)
#define XB(i)    (OFF_X + (i) * 131072)     // 0,1:h0  2,3:th0  4,5:h1  6,7:th1
#define OFF_B0   (OFF_X + 1048576)          // 1024 f32
#define OFF_C1   (OFF_B0 + 4096)            // 1024 f32

typedef _Float16 f16;
typedef unsigned long long ull;
typedef _Float16 v8h __attribute__((ext_vector_type(8)));
typedef float v4f __attribute__((ext_vector_type(4)));

union U2 { ull u[2]; v8h v; };
union P4 { f16 h[4]; ull u; };

__device__ __forceinline__ void st2(void* p, f16 v) {
  __hip_atomic_store((unsigned short*)p, __builtin_bit_cast(unsigned short, v),
                     __ATOMIC_RELAXED, __HIP_MEMORY_SCOPE_AGENT);
}
__device__ __forceinline__ ull ld8(const void* p) {
  return __hip_atomic_load((const ull*)p, __ATOMIC_RELAXED, __HIP_MEMORY_SCOPE_AGENT);
}

// pack value to f16 with 2-bit epoch tag in the mantissa LSBs
__device__ __forceinline__ f16 tagf(float v, unsigned tag) {
  unsigned short b = __builtin_bit_cast(unsigned short, (f16)v);
  b = (unsigned short)((b & 0xFFFCu) | (tag & 3u));
  return __builtin_bit_cast(f16, b);
}

__device__ __forceinline__ float rcpf(float x) {
#if __has_builtin(__builtin_amdgcn_rcpf)
  return __builtin_amdgcn_rcpf(x);
#else
  return 1.0f / x;
#endif
}
__device__ __forceinline__ float tanhfast(float x) {
  x = fminf(fmaxf(x, -20.0f), 20.0f);
  const float u = __expf(-2.0f * x);
  return 1.0f - 2.0f * u * rcpf(1.0f + u);
}

// clear exchange region to tag=2 pattern (first expected tags are 0/1 -> no ABA,
// also resets last replay's residue; runs every launch)
__global__ void k_init(uint2* p) {
  const uint2 v = { 0x00020002u, 0x00020002u };
  p[(size_t)blockIdx.x * 256 + threadIdx.x] = v;
}

// b0[i] = bi0+bh0 ; c1[i] = Wi1.bo0 + bi1 + bh1
__global__ void k_bias(const float* __restrict__ Wi, const float* __restrict__ bi,
                       const float* __restrict__ bh, const float* __restrict__ bo,
                       float* __restrict__ b0, float* __restrict__ c1) {
  const int i = blockIdx.x * 256 + threadIdx.x;
  const float* row = Wi + 1048576 + (size_t)i * 1024;
  float s = 0.f;
  for (int k = 0; k < 1024; k += 4) {
    const float4 w = *(const float4*)&row[k];
    const float4 v = *(const float4*)&bo[k];
    s += w.x * v.x + w.y * v.y + w.z * v.z + w.w * v.w;
  }
  c1[i] = s + bi[1024 + i] + bh[1024 + i];
  b0[i] = bi[i] + bh[i];
}

// M[i][d] = sum_k Wi1[i][k] * Wo0[k][d]   (fp32 compute, f16 store)
__global__ __launch_bounds__(256) void k_gemm_M(const float* __restrict__ Wi,
                                                const float* __restrict__ Wo,
                                                f16* __restrict__ Mh) {
  const float* A = Wi + 1048576;
  const float* B = Wo;
  __shared__ float As[16][68];
  __shared__ float Bs[16][68];
  const int bi = blockIdx.x >> 4, bj = blockIdx.x & 15;
  const int i0 = bi * 64, d0 = bj * 64;
  const int ti = threadIdx.x >> 4, tj = threadIdx.x & 15;
  float acc[4][4] = {};
  for (int kc = 0; kc < 1024; kc += 16) {
    const int r = threadIdx.x >> 2, cg = (threadIdx.x & 3) << 2;
    const float4 av = *(const float4*)&A[(size_t)(i0 + r) * 1024 + kc + cg];
    As[cg + 0][r] = av.x; As[cg + 1][r] = av.y; As[cg + 2][r] = av.z; As[cg + 3][r] = av.w;
    const int c2 = threadIdx.x >> 4, dg = (threadIdx.x & 15) << 2;
    const float4 bv = *(const float4*)&B[(size_t)(kc + c2) * 1024 + d0 + dg];
    *(float4*)&Bs[c2][dg] = bv;
    __syncthreads();
#pragma unroll
    for (int kk = 0; kk < 16; ++kk) {
      float a[4], b[4];
#pragma unroll
      for (int q = 0; q < 4; ++q) { a[q] = As[kk][ti * 4 + q]; b[q] = Bs[kk][tj * 4 + q]; }
#pragma unroll
      for (int p = 0; p < 4; ++p)
#pragma unroll
        for (int q = 0; q < 4; ++q) acc[p][q] += a[p] * b[q];
    }
    __syncthreads();
  }
#pragma unroll
  for (int p = 0; p < 4; ++p)
#pragma unroll
    for (int q = 0; q < 4; ++q)
      Mh[(size_t)(i0 + ti * 4 + p) * 1024 + (size_t)(d0 + tj * 4 + q)] = (f16)acc[p][q];
}

// z1(t) = x(t).Wi0^T + b0, f16, stored group-partitioned inside d_out slot t:
// byte(t,b,j) = t*SLOTB + (b>>4)*65536 + (b&15)*2048 + j*2
__global__ __launch_bounds__(256, 1) void k_z1(const float* __restrict__ x,
                                               const float* __restrict__ Wi,
                                               const float* __restrict__ b0p,
                                               float* __restrict__ dout) {
  const int t = blockIdx.x;
  const int tid = threadIdx.x, l = tid & 63, w = tid >> 6;
  const int lj = l & 15, lk = l >> 4;
  __shared__ __align__(16) f16 XL[64 * 1032];
  const float* xt = x + (size_t)t * SLOT;
  for (int u = tid; u < 16384; u += 256) {
    const int b = u >> 8, c4 = (u & 255) << 2;
    const float4 v = *(const float4*)&xt[(size_t)b * 1024 + c4];
    P4 p; p.h[0] = (f16)v.x; p.h[1] = (f16)v.y; p.h[2] = (f16)v.z; p.h[3] = (f16)v.w;
    *(ull*)&XL[b * 1032 + c4] = p.u;
  }
  __syncthreads();
  for (int jt = 0; jt < 16; ++jt) {
    const int jb = w * 256 + jt * 16;
    v4f acc[4] = {{0.f,0.f,0.f,0.f},{0.f,0.f,0.f,0.f},{0.f,0.f,0.f,0.f},{0.f,0.f,0.f,0.f}};
    for (int ks = 0; ks < 32; ++ks) {
      const int k0 = ks * 32 + lk * 8;
      const float* p = &Wi[(size_t)(jb + lj) * 1024 + k0];
      const float4 a = *(const float4*)p, b = *(const float4*)(p + 4);
      const v8h wf = {(f16)a.x,(f16)a.y,(f16)a.z,(f16)a.w,
                      (f16)b.x,(f16)b.y,(f16)b.z,(f16)b.w};
#pragma unroll
      for (int bt = 0; bt < 4; ++bt) {
        const v8h xf = *(const v8h*)&XL[(bt * 16 + lj) * 1032 + k0];
        acc[bt] = __builtin_amdgcn_mfma_f32_16x16x32_f16(xf, wf, acc[bt], 0, 0, 0);
      }
    }
    const float bias = b0p[jb + lj];
#pragma unroll
    for (int bt = 0; bt < 4; ++bt)
#pragma unroll
      for (int q = 0; q < 4; ++q) {
        const int b = bt * 16 + lk * 4 + q;
        f16* dst = (f16*)((char*)dout + (size_t)t * SLOTB + (size_t)(b >> 4) * 65536
                          + (size_t)(b & 15) * 2048) + (jb + lj);
        *dst = (f16)(acc[bt][q] + bias);
      }
  }
}

// ---- persistent RNN: 256 WGs (1/CU), LDS weights, NO flag barrier ----
// sync = epoch tags (2 LSBs of each exchanged f16); consumers poll their own
// fragments until tags match. Producers: plain tagged stores, no drain/flag.
__global__ __launch_bounds__(256, 1) void k_rnn(
    const float* __restrict__ Wh, const float* __restrict__ Wo,
    const float* __restrict__ bo,
    char* __restrict__ ws, float* __restrict__ dout)
{
  const f16* Mh = (const f16*)(ws + OFF_M);
  f16* h0b[2]  = { (f16*)(ws + XB(0)), (f16*)(ws + XB(1)) };
  f16* th0b[2] = { (f16*)(ws + XB(2)), (f16*)(ws + XB(3)) };
  f16* h1b[2]  = { (f16*)(ws + XB(4)), (f16*)(ws + XB(5)) };
  f16* th1b[2] = { (f16*)(ws + XB(6)), (f16*)(ws + XB(7)) };
  const float* c1p = (const float*)(ws + OFF_C1);

  const int wg = blockIdx.x;
  const int bq = wg & 3;
  const int jt = wg >> 2;
  const int j0 = jt * 16;
  const int tid = threadIdx.x;
  const int l = tid & 63, w = tid >> 6;
  const int lj = l & 15, lk = l >> 4;
  const int rb = tid >> 4, rj = tid & 15;

  __shared__ __align__(16) char WLb[4 * 32768];
  __shared__ float red[1024];

  // stage f32 mats: 0=Wh0, 2=Wh1, 3=Wo1; M (f16) -> mat 1  (same as R8)
  {
    const float* srcs[3] = { Wh, Wh + 1048576, Wo + 1048576 };
    const int mi[3] = { 0, 2, 3 };
#pragma unroll
    for (int m = 0; m < 3; ++m) {
      const float* src = srcs[m];
      for (int u = tid; u < 4096; u += 256) {
        const int j = u >> 8, c4 = (u & 255) << 2;
        const float4 v = *(const float4*)&src[(size_t)(j0 + j) * 1024 + c4];
        P4 p; p.h[0] = (f16)v.x; p.h[1] = (f16)v.y; p.h[2] = (f16)v.z; p.h[3] = (f16)v.w;
        *(ull*)(WLb + mi[m] * 32768 + ((c4 >> 3) << 8) + (j << 4) + ((c4 & 4) << 1)) = p.u;
      }
    }
    for (int u = tid; u < 2048; u += 256) {
      const int j = u >> 7, c8 = (u & 127) << 3;
      const v8h mv = *(const v8h*)&Mh[(size_t)(j0 + j) * 1024 + c8];
      *(v8h*)(WLb + 32768 + ((c8 >> 3) << 8) + (j << 4)) = mv;
    }
  }
  const float c1v = c1p[j0 + rj];
  const float bo1v = bo[1024 + j0 + rj];
  __syncthreads();

  const size_t actbase = (size_t)(bq * 16 + lj) * 1024 + (size_t)(w * 256 + lk * 8);
  const int redw = w * 256 + lk * 64 + lj;
  const size_t rdst = (size_t)(bq * 16 + rb) * 1024 + (size_t)(j0 + rj);
  const int fbase = ((w * 32 + lk) << 8) + (lj << 4);

  auto wfrag = [&](int m, int s) -> v8h {
    return *(const v8h*)(WLb + m * 32768 + fbase + (s << 10));
  };
  auto zptr = [&](int t) -> const f16* {
    return (const f16*)((const char*)dout + (size_t)t * SLOTB + (size_t)bq * 65536
                        + (size_t)rb * 2048) + (j0 + rj);
  };
  auto reduce4 = [&](v4f a) -> float {
    __syncthreads();
#pragma unroll
    for (int q = 0; q < 4; ++q) red[redw + q * 16] = a[q];
    __syncthreads();
    return red[tid] + red[256 + tid] + red[512 + tid] + red[768 + tid];
  };

  // poll one matrix's fragments until every f16's 2-bit tag matches
  auto pollfr = [&](const f16* base, unsigned tag, v8h out[8]) {
    const ull mask = 0x0003000300030003ULL;
    const ull expv = 0x0001000100010001ULL * (ull)(tag & 3u);
    ull u0[8], u1[8];
    for (;;) {
#pragma unroll
      for (int s = 0; s < 8; ++s) { u0[s] = ld8(base + s * 32); u1[s] = ld8(base + s * 32 + 4); }
      int ok = 1;
#pragma unroll
      for (int s = 0; s < 8; ++s)
        ok &= ((u0[s] & mask) == expv) & ((u1[s] & mask) == expv);
      if (__all(ok)) break;
    }
#pragma unroll
    for (int s = 0; s < 8; ++s) { U2 c; c.u[0] = u0[s]; c.u[1] = u1[s]; out[s] = c.v; }
  };
  auto pollfr2 = [&](const f16* bA, const f16* bB, unsigned tag, v8h oA[8], v8h oB[8]) {
    const ull mask = 0x0003000300030003ULL;
    const ull expv = 0x0001000100010001ULL * (ull)(tag & 3u);
    ull a0[8], a1[8], b0_[8], b1_[8];
    for (;;) {
#pragma unroll
      for (int s = 0; s < 8; ++s) {
        a0[s] = ld8(bA + s * 32); a1[s] = ld8(bA + s * 32 + 4);
        b0_[s] = ld8(bB + s * 32); b1_[s] = ld8(bB + s * 32 + 4);
      }
      int ok = 1;
#pragma unroll
      for (int s = 0; s < 8; ++s) {
        ok &= ((a0[s] & mask) == expv) & ((a1[s] & mask) == expv);
        ok &= ((b0_[s] & mask) == expv) & ((b1_[s] & mask) == expv);
      }
      if (__all(ok)) break;
    }
#pragma unroll
    for (int s = 0; s < 8; ++s) {
      U2 c; c.u[0] = a0[s]; c.u[1] = a1[s]; oA[s] = c.v;
      U2 d; d.u[0] = b0_[s]; d.u[1] = b1_[s]; oB[s] = d.v;
    }
  };

  float zv = (float)(*zptr(0));

  for (int t = 0; t < TT; ++t) {
    const bool R = (t > 0);
    const unsigned tg = (unsigned)t & 3u;

    // ---- phase A: h0 = z1(t) + Wh0 * th1(t-1) ----
    v4f accA = {0.f, 0.f, 0.f, 0.f};
    if (R) {
      v8h thf[8];
      pollfr(th1b[(t - 1) & 1] + actbase, (unsigned)(t - 1) & 3u, thf);
#pragma unroll
      for (int s = 0; s < 8; ++s)
        accA = __builtin_amdgcn_mfma_f32_16x16x32_f16(thf[s], wfrag(0, s), accA, 0, 0, 0);
    }
    const float h0 = reduce4(accA) + zv;
    st2(&h0b[t & 1][rdst], tagf(h0, tg));
    st2(&th0b[t & 1][rdst], tagf(tanhfast(h0), tg));

    // ---- window: z1(t+1) prefetch + outs(t-1) = Wo1*h1(t-1) + bo1 ----
    float zn = 0.f;
    if (t + 1 < TT) zn = (float)(*zptr(t + 1));
    if (R) {
      v8h hrf[8];
      pollfr(h1b[(t - 1) & 1] + actbase, (unsigned)(t - 1) & 3u, hrf);
      v4f aa = {0.f, 0.f, 0.f, 0.f};
#pragma unroll
      for (int s = 0; s < 8; ++s)
        aa = __builtin_amdgcn_mfma_f32_16x16x32_f16(hrf[s], wfrag(3, s), aa, 0, 0, 0);
      dout[(size_t)(t - 1) * SLOT + rdst] = reduce4(aa) + bo1v;   // plain store
    }

    // ---- phase B: h1 = M*h0 + Wh1*th0 + c1 ----
    v8h g0f[8], t0f[8];
    pollfr2(h0b[t & 1] + actbase, th0b[t & 1] + actbase, tg, g0f, t0f);
    v4f aM = {0.f, 0.f, 0.f, 0.f}, aW = {0.f, 0.f, 0.f, 0.f};
#pragma unroll
    for (int s = 0; s < 8; ++s) {
      aM = __builtin_amdgcn_mfma_f32_16x16x32_f16(g0f[s], wfrag(1, s), aM, 0, 0, 0);
      aW = __builtin_amdgcn_mfma_f32_16x16x32_f16(t0f[s], wfrag(2, s), aW, 0, 0, 0);
    }
    const float h1 = reduce4(aM + aW) + c1v;
    const float th1v = tanhfast(h1);
    st2(&h1b[t & 1][rdst], tagf(h1, tg));
    st2(&th1b[t & 1][rdst], tagf(th1v, tg));
    if (t == TT - 1) dout[FINALOFF + rdst] = th1v;                // plain store
    zv = zn;
  }

  // ---- epilogue: outs(TT-1) = Wo1 * h1(TT-1) + bo1 ----
  {
    v8h hrf[8];
    pollfr(h1b[(TT - 1) & 1] + actbase, (unsigned)(TT - 1) & 3u, hrf);
    v4f aa = {0.f, 0.f, 0.f, 0.f};
#pragma unroll
    for (int s = 0; s < 8; ++s)
      aa = __builtin_amdgcn_mfma_f32_16x16x32_f16(hrf[s], wfrag(3, s), aa, 0, 0, 0);
    dout[(size_t)(TT - 1) * SLOT + rdst] = reduce4(aa) + bo1v;
  }
}

extern "C" void kernel_launch(void* const* d_in, const int* in_sizes, int n_in,
                              void* d_out, int out_size, void* d_ws, size_t ws_size,
                              hipStream_t stream) {
  (void)in_sizes; (void)n_in; (void)out_size; (void)ws_size;
  const float* x  = (const float*)d_in[0];
  const float* Wi = (const float*)d_in[1];
  const float* bi = (const float*)d_in[2];
  const float* Wh = (const float*)d_in[3];
  const float* bh = (const float*)d_in[4];
  const float* Wo = (const float*)d_in[5];
  const float* bo = (const float*)d_in[6];
  char* ws = (char*)d_ws;
  float* out = (float*)d_out;

  k_init<<<512, 256, 0, stream>>>((uint2*)(ws + OFF_X));   // clears 1 MiB exchange region
  k_bias<<<4, 256, 0, stream>>>(Wi, bi, bh, bo, (float*)(ws + OFF_B0), (float*)(ws + OFF_C1));
  k_gemm_M<<<256, 256, 0, stream>>>(Wi, Wo, (f16*)(ws + OFF_M));
  k_z1<<<512, 256, 0, stream>>>(x, Wi, (const float*)(ws + OFF_B0), out);
  k_rnn<<<NWG, 256, 0, stream>>>(Wh, Wo, bo, ws, out);
}